// Round 5
// baseline (203.340 us; speedup 1.0000x reference)
//
#include <hip/hip_runtime.h>
#include <math.h>

#define DD 160
#define HH 192
#define WW 160
#define TW 32          // block tile width  (16 w-pairs)
#define THB 16         // block tile height
#define TD 8           // slices per block -> 1200 blocks
#define HW (HH * WW)
#define NVOX (DD * HW)

typedef float v2f __attribute__((ext_vector_type(2)));

__device__ __forceinline__ v2f vrcp(v2f a) {
    v2f r;
    r.x = __builtin_amdgcn_rcpf(a.x);
    r.y = __builtin_amdgcn_rcpf(a.y);
    return r;
}

// packed atan(num/den) with a SINGLE rcp: x = min(|n|,|d|) * rcp(max(|n|,|d|)),
// odd minimax poly on [0,1], quadrant select on |n|>|d|, sign = sgn(n)^sgn(d).
// err ~1e-5 rad (validated: absmax 0.0 vs harness threshold through R2/R3).
__device__ __forceinline__ v2f atan_ratio(v2f num, v2f den) {
    v2f a = __builtin_elementwise_abs(num);
    v2f b = __builtin_elementwise_abs(den);
    v2f mn = __builtin_elementwise_min(a, b);
    v2f mx = __builtin_elementwise_max(a, b);
    v2f x = mn * vrcp(mx);
    v2f x2 = x * x;
    v2f p = __builtin_elementwise_fma(x2,
            __builtin_elementwise_fma(x2,
            __builtin_elementwise_fma(x2,
            __builtin_elementwise_fma(x2,
            __builtin_elementwise_fma(x2, (v2f)(-0.0117212f), (v2f)(0.05265332f)),
            (v2f)(-0.11643287f)), (v2f)(0.19354346f)), (v2f)(-0.33262347f)),
            (v2f)(0.99997726f));
    p *= x;
    v2f q = 1.57079632679489662f - p;
    v2f res;
    res.x = a.x > b.x ? q.x : p.x;   // res >= 0 here
    res.y = a.y > b.y ? q.y : p.y;
    unsigned sx = (__float_as_uint(num.x) ^ __float_as_uint(den.x)) & 0x80000000u;
    unsigned sy = (__float_as_uint(num.y) ^ __float_as_uint(den.y)) & 0x80000000u;
    res.x = __uint_as_float(__float_as_uint(res.x) | sx);
    res.y = __uint_as_float(__float_as_uint(res.y) | sy);
    return res;
}

struct Part { v2f Px, Py, B, C; };

// R12: NO LDS, NO barriers. R0-R3 invariant: ~41us whenever the barrier-
// staged LDS pipeline exists, independent of grid size (R1), instruction
// count (R2), per-thread work (R3), and even with all inputs L3-resident
// (R1 replay). The stage convoy IS the clock. This version reads the 3x3
// window straight from global (L1/L2 serve the 3x h-overlap; BW has huge
// headroom), keeps the per-plane partials register ring, and has zero
// __syncthreads in the main loop -> waves fully independent, TLP hides
// latency.
__global__ __launch_bounds__(256) void demons_ori_kernel(
    const float* __restrict__ Mv, const float* __restrict__ Sv,
    const float* __restrict__ flow, float* __restrict__ out)
{
    __shared__ float redbuf[4];

    const int tid = threadIdx.x;
    const int lane = tid & 63;
    const int wid = tid >> 6;
    const int i16 = tid & 15;              // w-pair index
    const int r   = tid >> 4;              // row 0..15
    const int gw  = blockIdx.x * TW + 2 * i16;   // even -> all v2f 8B aligned
    const int gh  = blockIdx.y * THB + r;
    const int d0  = blockIdx.z * TD;

    // in-plane column predication (reference conv zero-pads)
    const bool okL = (gw >= 2);            // left v2f covers cols gw-2,gw-1
    const bool okR = (gw + 3 < WW);        // right v2f covers cols gw+2,gw+3
    const bool okU = (gh >= 1);            // row gh-1
    const bool okD = (gh + 1 < HH);        // row gh+1

    // partials of one field's plane d for the pair (gw,gw+1) at row gh.
    // 9 predicated 8B global loads; horizontal windows packed.
    auto planeField = [&](const float* __restrict__ f, int d, Part& P) {
        const bool din = ((unsigned)d < (unsigned)DD);
        const float* pc = f + (long)d * HW + (long)gh * WW + gw;
        v2f zero = (v2f)(0.f);
        v2f X0, X1, X2, W0, W2, I0, I1, I2, Cmid;
        {   // row gh-1
            const float* p = pc - WW;
            bool rok = din && okU;
            v2f L = (rok && okL) ? *(const v2f*)(p - 2) : zero;
            v2f C = rok ? *(const v2f*)p : zero;
            v2f R = (rok && okR) ? *(const v2f*)(p + 2) : zero;
            v2f cA = (v2f){L.y, C.x};
            v2f cC = (v2f){C.y, R.x};
            v2f s = cA + cC;
            X0 = cC - cA;
            W0 = __builtin_elementwise_fma(C, (v2f)(2.f), s);
            I0 = s + C;
        }
        {   // row gh
            const float* p = pc;
            v2f L = (din && okL) ? *(const v2f*)(p - 2) : zero;
            v2f C = din ? *(const v2f*)p : zero;
            v2f R = (din && okR) ? *(const v2f*)(p + 2) : zero;
            v2f cA = (v2f){L.y, C.x};
            v2f cC = (v2f){C.y, R.x};
            v2f s = cA + cC;
            X1 = cC - cA;
            I1 = s + C;
            Cmid = C;
        }
        {   // row gh+1
            const float* p = pc + WW;
            bool rok = din && okD;
            v2f L = (rok && okL) ? *(const v2f*)(p - 2) : zero;
            v2f C = rok ? *(const v2f*)p : zero;
            v2f R = (rok && okR) ? *(const v2f*)(p + 2) : zero;
            v2f cA = (v2f){L.y, C.x};
            v2f cC = (v2f){C.y, R.x};
            v2f s = cA + cC;
            X2 = cC - cA;
            W2 = __builtin_elementwise_fma(C, (v2f)(2.f), s);
            I2 = s + C;
        }
        P.Px = __builtin_elementwise_fma(X1, (v2f)(2.f), X0) + X2;
        P.Py = W2 - W0;
        P.B  = __builtin_elementwise_fma(I1, (v2f)(2.f), I0) + I2;
        P.C  = Cmid;
    };

    // register ring over z: planes {m,z,p} x fields {S,M}
    Part mS, zS, pS, mM, zM, pM;
    planeField(Sv, d0 - 1, mS);
    planeField(Mv, d0 - 1, mM);
    planeField(Sv, d0, zS);
    planeField(Mv, d0, zM);

    const size_t voff = (size_t)gh * WW + gw;
    v2f fFx, fFy, fFz;
    {
        size_t o = (size_t)d0 * HW + voff;
        fFx = *(const v2f*)(flow + o);
        fFy = *(const v2f*)(flow + NVOX + o);
        fFz = *(const v2f*)(flow + 2 * (size_t)NVOX + o);
    }

    v2f vsum = (v2f){0.f, 0.f};

    #pragma unroll
    for (int dd = 0; dd < TD; ++dd) {
        const int d = d0 + dd;
        planeField(Sv, d + 1, pS);
        planeField(Mv, d + 1, pM);
        v2f nFx = (v2f){0.f, 0.f}, nFy = nFx, nFz = nFx;
        if (dd < TD - 1) {
            size_t o = (size_t)(d + 1) * HW + voff;
            nFx = *(const v2f*)(flow + o);
            nFy = *(const v2f*)(flow + NVOX + o);
            nFz = *(const v2f*)(flow + 2 * (size_t)NVOX + o);
        }

        v2f idf = zM.C - zS.C;
        v2f i2  = __builtin_elementwise_fma(idf, idf, (v2f)(1e-10f));
        v2f gxS = mS.Px + zS.Px + pS.Px;
        v2f gyS = mS.Py + zS.Py + pS.Py;
        v2f gzS = pS.B - mS.B;
        v2f gxM = mM.Px + zM.Px + pM.Px;
        v2f gyM = mM.Py + zM.Py + pM.Py;
        v2f gzM = pM.B - mM.B;
        v2f denS = __builtin_elementwise_fma(gxS, gxS,
                   __builtin_elementwise_fma(gyS, gyS,
                   __builtin_elementwise_fma(gzS, gzS, i2)));
        v2f denM = __builtin_elementwise_fma(gxM, gxM,
                   __builtin_elementwise_fma(gyM, gyM,
                   __builtin_elementwise_fma(gzM, gzM, i2)));
        v2f rS = vrcp(denS);
        v2f rM = vrcp(denM);
        v2f Ux = idf * __builtin_elementwise_fma(gxS, rS, gxM * rM);
        v2f Uy = idf * __builtin_elementwise_fma(gyS, rS, gyM * rM);
        v2f Uz = idf * __builtin_elementwise_fma(gzS, rS, gzM * rM);

        v2f uzp = Uz + 1e-10f;
        v2f dxz = atan_ratio(Ux, uzp);
        v2f dyz = atan_ratio(Uy, uzp);

        v2f fzp = fFz + 1e-10f;
        v2f fxz = atan_ratio(fFx, fzp);
        v2f fyz = atan_ratio(fFy, fzp);

        v2f e1 = fxz - dxz;
        v2f e2 = fyz - dyz;
        vsum = __builtin_elementwise_fma(e1, e1,
               __builtin_elementwise_fma(e2, e2, vsum));

        // rotate ring (full unroll renames)
        mS = zS; zS = pS;
        mM = zM; zM = pM;
        fFx = nFx; fFy = nFy; fFz = nFz;
    }

    float lsum = vsum.x + vsum.y;
    // wave shuffle reduce -> per-wave LDS slot -> one atomic per block
    #pragma unroll
    for (int o = 32; o > 0; o >>= 1)
        lsum += __shfl_down(lsum, o, 64);
    if (lane == 0)
        redbuf[wid] = lsum;
    __syncthreads();
    if (tid == 0) {
        float s = redbuf[0] + redbuf[1] + redbuf[2] + redbuf[3];
        atomicAdd(out, s * (1.0f / (float)NVOX));
    }
}

extern "C" void kernel_launch(void* const* d_in, const int* in_sizes, int n_in,
                              void* d_out, int out_size, void* d_ws, size_t ws_size,
                              hipStream_t stream) {
    const float* Mv   = (const float*)d_in[0];
    const float* Sv   = (const float*)d_in[1];
    const float* flow = (const float*)d_in[2];
    float* out = (float*)d_out;

    hipMemsetAsync(out, 0, sizeof(float), stream);

    dim3 grid(WW / TW, HH / THB, DD / TD);   // 5 x 12 x 20 = 1200 blocks
    demons_ori_kernel<<<grid, dim3(256), 0, stream>>>(Mv, Sv, flow, out);
}

// Round 6
// 156.685 us; speedup vs baseline: 1.2978x; 1.2978x over previous
//
#include <hip/hip_runtime.h>
#include <math.h>

#define DD 160
#define HH 192
#define WW 160
#define TW 32          // block tile width (16 w-pairs/wave)
#define THB 16         // block tile height (4 waves x 4 rows)
#define TD 8           // slices per block -> 1200 blocks
#define HW (HH * WW)
#define NVOX (DD * HW)
#define WROWS 4        // voxel rows per wave
#define WHR 6          // halo rows per wave  (rows -1..+4)
#define WHW 34         // halo cols
#define WHALO (WHR * WHW)   // 204 staging slots per wave per field
#define WSTR 208       // padded wave region size (floats), keeps 8B alignment

typedef float v2f __attribute__((ext_vector_type(2)));

__device__ __forceinline__ v2f vrcp(v2f a) {
    v2f r;
    r.x = __builtin_amdgcn_rcpf(a.x);
    r.y = __builtin_amdgcn_rcpf(a.y);
    return r;
}

// packed atan(num/den) with a SINGLE rcp: x = min(|n|,|d|) * rcp(max(|n|,|d|)),
// odd minimax poly on [0,1], quadrant select on |n|>|d|, sign = sgn(n)^sgn(d).
// err ~1e-5 rad (absmax 0.0 vs harness threshold through R2-R4).
__device__ __forceinline__ v2f atan_ratio(v2f num, v2f den) {
    v2f a = __builtin_elementwise_abs(num);
    v2f b = __builtin_elementwise_abs(den);
    v2f mn = __builtin_elementwise_min(a, b);
    v2f mx = __builtin_elementwise_max(a, b);
    v2f x = mn * vrcp(mx);
    v2f x2 = x * x;
    v2f p = __builtin_elementwise_fma(x2,
            __builtin_elementwise_fma(x2,
            __builtin_elementwise_fma(x2,
            __builtin_elementwise_fma(x2,
            __builtin_elementwise_fma(x2, (v2f)(-0.0117212f), (v2f)(0.05265332f)),
            (v2f)(-0.11643287f)), (v2f)(0.19354346f)), (v2f)(-0.33262347f)),
            (v2f)(0.99997726f));
    p *= x;
    v2f q = 1.57079632679489662f - p;
    v2f res;
    res.x = a.x > b.x ? q.x : p.x;   // res >= 0 here
    res.y = a.y > b.y ? q.y : p.y;
    unsigned sx = (__float_as_uint(num.x) ^ __float_as_uint(den.x)) & 0x80000000u;
    unsigned sy = (__float_as_uint(num.y) ^ __float_as_uint(den.y)) & 0x80000000u;
    res.x = __uint_as_float(__float_as_uint(res.x) | sx);
    res.y = __uint_as_float(__float_as_uint(res.y) | sy);
    return res;
}

struct Part { v2f Px, Py, B, C; };

// R13: WAVE-PRIVATE halo staging, ZERO barriers in the main loop.
// R0-R4 synthesis: the ~41us invariant came from `issue(); __syncthreads()`
// -- the compiler emits s_waitcnt vmcnt(0) before s_barrier, so the
// "distance-1 prefetch" was force-drained inside the SAME stage, and the
// barrier convoyed all 4 waves onto that drain. Here each wave stages its
// own 6x34 halo (double-buffered) into its own LDS region; within-wave
// ds_write->ds_read ordering is automatic, so no barrier is needed and the
// prefetch genuinely flies for a whole stage while waves drift in phase.
__global__ __launch_bounds__(256) void demons_ori_kernel(
    const float* __restrict__ Mv, const float* __restrict__ Sv,
    const float* __restrict__ flow, float* __restrict__ out)
{
    __shared__ float buf[4][2][2][WSTR];   // [wave][parity][field][slot]
    __shared__ float redbuf[4];

    const int tid = threadIdx.x;
    const int lane = tid & 63;
    const int wid = tid >> 6;
    const int i16 = lane & 15;             // w-pair index 0..15
    const int rloc = lane >> 4;            // voxel row within wave 0..3
    const int tw2 = 2 * i16;
    const int w0 = blockIdx.x * TW;
    const int hbase = blockIdx.y * THB + wid * WROWS;  // wave's first voxel row
    const int gh = hbase + rloc;
    const int d0 = blockIdx.z * TD;

    // slice-invariant staging slots: lane + 64*s, s=0..2 always, s=3 lane<12
    const bool has3 = (lane < WHALO - 192);   // lanes 0..11
    int gb[4]; bool ok[4];
    #pragma unroll
    for (int s = 0; s < 4; ++s) {
        int i = lane + 64 * s;
        int hh = i / WHW, ww = i - WHW * hh;
        int ghs = hbase + hh - 1, gws = w0 + ww - 1;
        bool act = (s < 3) || has3;
        ok[s] = act && (ghs >= 0) && (ghs < HH) && (gws >= 0) && (gws < WW);
        gb[s] = ghs * WW + gws;
    }

    // distance-1 prefetch regs (constant-indexed -> VGPRs)
    float hS[4], hM[4];

    auto issue = [&](int d) {
        const bool din = ((unsigned)d < (unsigned)DD);
        const size_t base = (size_t)d * HW;
        #pragma unroll
        for (int s = 0; s < 4; ++s) {
            bool o = din && ok[s];
            hS[s] = o ? Sv[base + gb[s]] : 0.f;
            hM[s] = o ? Mv[base + gb[s]] : 0.f;
        }
    };
    auto commit = [&](int d) {
        float* __restrict__ bS = &buf[wid][d & 1][0][0];
        float* __restrict__ bM = &buf[wid][d & 1][1][0];
        #pragma unroll
        for (int s = 0; s < 3; ++s) {
            bS[lane + 64 * s] = hS[s];
            bM[lane + 64 * s] = hM[s];
        }
        if (has3) { bS[lane + 192] = hS[3]; bM[lane + 192] = hM[3]; }
    };

    // stencil window: wave-region rows rloc..rloc+2, cols tw2..tw2+3
    // (two aligned v2f per row; all offsets 8B aligned: rloc*34+tw2 even)
    const int rb = rloc * WHW + tw2;
    auto fieldPartials = [&](const float* __restrict__ b, Part& P) {
        const float* p0 = b + rb;
        const float* p1 = p0 + WHW;
        const float* p2 = p1 + WHW;
        v2f lo0 = *(const v2f*)p0, hi0 = *(const v2f*)(p0 + 2);
        v2f lo1 = *(const v2f*)p1, hi1 = *(const v2f*)(p1 + 2);
        v2f lo2 = *(const v2f*)p2, hi2 = *(const v2f*)(p2 + 2);
        v2f X0 = hi0 - lo0, X1 = hi1 - lo1, X2 = hi2 - lo2;
        v2f m0 = (v2f){lo0.y, hi0.x};
        v2f m1 = (v2f){lo1.y, hi1.x};
        v2f m2 = (v2f){lo2.y, hi2.x};
        v2f s0 = lo0 + hi0, s1 = lo1 + hi1, s2 = lo2 + hi2;
        v2f W0 = __builtin_elementwise_fma(m0, (v2f)(2.f), s0);
        v2f W2 = __builtin_elementwise_fma(m2, (v2f)(2.f), s2);
        v2f I0 = s0 + m0, I1 = s1 + m1, I2 = s2 + m2;
        P.Px = __builtin_elementwise_fma(X1, (v2f)(2.f), X0) + X2;  // vert [1,2,1] of X
        P.Py = W2 - W0;                                             // vert [-1,0,1] of W
        P.B  = __builtin_elementwise_fma(I1, (v2f)(2.f), I0) + I2;  // vert [1,2,1] of I
        P.C  = m1;                                                  // center values
    };

    // register ring over z: planes {m,z,p} x fields {S,M}
    Part mS, zS, pS, mM, zM, pM;

    // ---- warmup: loads always issued BEFORE the partials they overlap ----
    issue(d0 - 1);
    commit(d0 - 1);          // only fully-exposed vmcnt wait of the block
    issue(d0);               // in flight across partials(m)
    fieldPartials(&buf[wid][(d0 - 1) & 1][0][0], mS);
    fieldPartials(&buf[wid][(d0 - 1) & 1][1][0], mM);
    commit(d0);
    issue(d0 + 1);           // in flight across partials(z)
    fieldPartials(&buf[wid][d0 & 1][0][0], zS);
    fieldPartials(&buf[wid][d0 & 1][1][0], zM);

    const size_t voff = (size_t)gh * WW + (w0 + tw2);   // pair contiguous
    v2f fFx, fFy, fFz;
    {
        size_t o = (size_t)d0 * HW + voff;
        fFx = *(const v2f*)(flow + o);
        fFy = *(const v2f*)(flow + NVOX + o);
        fFz = *(const v2f*)(flow + 2 * (size_t)NVOX + o);
    }

    v2f vsum = (v2f){0.f, 0.f};

    #pragma unroll
    for (int dd = 0; dd < TD; ++dd) {
        const int d = d0 + dd;
        commit(d + 1);       // vmcnt wait for loads in flight since last stage
        v2f nFx = (v2f){0.f, 0.f}, nFy = nFx, nFz = nFx;
        if (dd < TD - 1) {
            issue(d + 2);    // flies across this whole stage (no barrier drain!)
            size_t o = (size_t)(d + 1) * HW + voff;
            nFx = *(const v2f*)(flow + o);
            nFy = *(const v2f*)(flow + NVOX + o);
            nFz = *(const v2f*)(flow + 2 * (size_t)NVOX + o);
        }
        // within-wave lgkmcnt orders commit's ds_writes before these reads
        fieldPartials(&buf[wid][(d + 1) & 1][0][0], pS);
        fieldPartials(&buf[wid][(d + 1) & 1][1][0], pM);

        v2f idf = zM.C - zS.C;
        v2f i2  = __builtin_elementwise_fma(idf, idf, (v2f)(1e-10f));
        v2f gxS = mS.Px + zS.Px + pS.Px;
        v2f gyS = mS.Py + zS.Py + pS.Py;
        v2f gzS = pS.B - mS.B;
        v2f gxM = mM.Px + zM.Px + pM.Px;
        v2f gyM = mM.Py + zM.Py + pM.Py;
        v2f gzM = pM.B - mM.B;
        v2f denS = __builtin_elementwise_fma(gxS, gxS,
                   __builtin_elementwise_fma(gyS, gyS,
                   __builtin_elementwise_fma(gzS, gzS, i2)));
        v2f denM = __builtin_elementwise_fma(gxM, gxM,
                   __builtin_elementwise_fma(gyM, gyM,
                   __builtin_elementwise_fma(gzM, gzM, i2)));
        v2f rS = vrcp(denS);
        v2f rM = vrcp(denM);
        v2f Ux = idf * __builtin_elementwise_fma(gxS, rS, gxM * rM);
        v2f Uy = idf * __builtin_elementwise_fma(gyS, rS, gyM * rM);
        v2f Uz = idf * __builtin_elementwise_fma(gzS, rS, gzM * rM);

        v2f uzp = Uz + 1e-10f;
        v2f dxz = atan_ratio(Ux, uzp);
        v2f dyz = atan_ratio(Uy, uzp);

        v2f fzp = fFz + 1e-10f;
        v2f fxz = atan_ratio(fFx, fzp);
        v2f fyz = atan_ratio(fFy, fzp);

        v2f e1 = fxz - dxz;
        v2f e2 = fyz - dyz;
        vsum = __builtin_elementwise_fma(e1, e1,
               __builtin_elementwise_fma(e2, e2, vsum));

        // rotate ring (full unroll renames)
        mS = zS; zS = pS;
        mM = zM; zM = pM;
        fFx = nFx; fFy = nFy; fFz = nFz;
    }

    float lsum = vsum.x + vsum.y;
    // wave shuffle reduce -> per-wave LDS slot -> one atomic per block
    #pragma unroll
    for (int o = 32; o > 0; o >>= 1)
        lsum += __shfl_down(lsum, o, 64);
    if (lane == 0)
        redbuf[wid] = lsum;
    __syncthreads();   // only barrier in the kernel (final reduction)
    if (tid == 0) {
        float s = redbuf[0] + redbuf[1] + redbuf[2] + redbuf[3];
        atomicAdd(out, s * (1.0f / (float)NVOX));
    }
}

extern "C" void kernel_launch(void* const* d_in, const int* in_sizes, int n_in,
                              void* d_out, int out_size, void* d_ws, size_t ws_size,
                              hipStream_t stream) {
    const float* Mv   = (const float*)d_in[0];
    const float* Sv   = (const float*)d_in[1];
    const float* flow = (const float*)d_in[2];
    float* out = (float*)d_out;

    hipMemsetAsync(out, 0, sizeof(float), stream);

    dim3 grid(WW / TW, HH / THB, DD / TD);   // 5 x 12 x 20 = 1200 blocks
    demons_ori_kernel<<<grid, dim3(256), 0, stream>>>(Mv, Sv, flow, out);
}

// Round 7
// 154.182 us; speedup vs baseline: 1.3188x; 1.0162x over previous
//
#include <hip/hip_runtime.h>
#include <math.h>

#define DD 160
#define HH 192
#define WW 160
#define TW 32          // block tile width
#define THB 16         // block tile height (16 rows x 16 w-pairs = 256 threads)
#define TD 8           // slices per block -> 1200 blocks (R1: more/smaller lost)
#define HW (HH * WW)
#define NVOX (DD * HW)
#define HTW 34         // halo cols
#define HTH 18         // halo rows
#define LSTR 34        // row stride == HTW keeps staging LINEAR (bS[tid])
#define HALO (HTH * HTW)   // 612

typedef float v2f __attribute__((ext_vector_type(2)));

__device__ __forceinline__ v2f vrcp(v2f a) {
    v2f r;
    r.x = __builtin_amdgcn_rcpf(a.x);
    r.y = __builtin_amdgcn_rcpf(a.y);
    return r;
}

// packed atan(num/den) with a SINGLE rcp: x = min(|n|,|d|) * rcp(max(|n|,|d|)),
// odd minimax poly on [0,1], quadrant select on |n|>|d|, sign = sgn(n)^sgn(d).
// err ~1e-5 rad (absmax 0.0 vs harness threshold through R2-R5).
__device__ __forceinline__ v2f atan_ratio(v2f num, v2f den) {
    v2f a = __builtin_elementwise_abs(num);
    v2f b = __builtin_elementwise_abs(den);
    v2f mn = __builtin_elementwise_min(a, b);
    v2f mx = __builtin_elementwise_max(a, b);
    v2f x = mn * vrcp(mx);
    v2f x2 = x * x;
    v2f p = __builtin_elementwise_fma(x2,
            __builtin_elementwise_fma(x2,
            __builtin_elementwise_fma(x2,
            __builtin_elementwise_fma(x2,
            __builtin_elementwise_fma(x2, (v2f)(-0.0117212f), (v2f)(0.05265332f)),
            (v2f)(-0.11643287f)), (v2f)(0.19354346f)), (v2f)(-0.33262347f)),
            (v2f)(0.99997726f));
    p *= x;
    v2f q = 1.57079632679489662f - p;
    v2f res;
    res.x = a.x > b.x ? q.x : p.x;   // res >= 0 here
    res.y = a.y > b.y ? q.y : p.y;
    unsigned sx = (__float_as_uint(num.x) ^ __float_as_uint(den.x)) & 0x80000000u;
    unsigned sy = (__float_as_uint(num.y) ^ __float_as_uint(den.y)) & 0x80000000u;
    res.x = __uint_as_float(__float_as_uint(res.x) | sx);
    res.y = __uint_as_float(__float_as_uint(res.y) | sy);
    return res;
}

// R14: identical to the 41us R2 baseline EXCEPT the stage ordering.
// OLD: commit; issue; flow; barrier; partials; compute
//   -> issue sat right before the barrier; the compiler's mandatory
//      s_waitcnt vmcnt(0) before s_barrier force-drained the prefetch
//      INSIDE the same stage: ~900cyc exposed memory wait per stage,
//      convoying all 4 waves. This was the invariant R0-R5 kept hitting.
// NEW: commit; barrier; issue; flow; partials; compute
//   -> zero outstanding VMEM at the barrier (drain is free); the prefetch
//      flies across partials+compute and is mostly landed when next
//      stage's commit waits on it.
__global__ __launch_bounds__(256) void demons_ori_kernel(
    const float* __restrict__ Mv, const float* __restrict__ Sv,
    const float* __restrict__ flow, float* __restrict__ out)
{
    __shared__ float buf[2][2][HTH * LSTR];   // [parity][field][h*LSTR+w]
    __shared__ float redbuf[4];

    const int tid = threadIdx.x;
    const int lane = tid & 63;
    const int wid = tid >> 6;
    const int i16 = lane & 15;                  // w-pair index 0..15
    const int r   = wid * 4 + (lane >> 4);      // voxel row 0..15
    const int tw2 = 2 * i16;                    // block-local first col of pair
    const int w0 = blockIdx.x * TW;
    const int h0 = blockIdx.y * THB;
    const int d0 = blockIdx.z * TD;

    // slice-invariant staging slots: tid, tid+256, tid+512 (612 total)
    const bool has2 = (tid < HALO - 512);   // tids 0..99
    int gb0, gb1, gb2 = 0;
    bool ok0, ok1, ok2 = false;
    {
        int i = tid;
        int hh = i / HTW, ww = i - HTW * hh;
        int gh = h0 + hh - 1, gw = w0 + ww - 1;
        ok0 = (gh >= 0 && gh < HH && gw >= 0 && gw < WW);
        gb0 = gh * WW + gw;
        i = tid + 256;
        hh = i / HTW; ww = i - HTW * hh;
        gh = h0 + hh - 1; gw = w0 + ww - 1;
        ok1 = (gh >= 0 && gh < HH && gw >= 0 && gw < WW);
        gb1 = gh * WW + gw;
        if (has2) {
            i = tid + 512;
            hh = i / HTW; ww = i - HTW * hh;
            gh = h0 + hh - 1; gw = w0 + ww - 1;
            ok2 = (gh >= 0 && gh < HH && gw >= 0 && gw < WW);
            gb2 = gh * WW + gw;
        }
    }

    // distance-1 prefetch set — named scalars only
    float pS0 = 0.f, pM0 = 0.f, pS1 = 0.f, pM1 = 0.f, pS2 = 0.f, pM2 = 0.f;

    auto issue = [&](int d) {
        const bool din = (d >= 0) && (d < DD);
        const size_t base = (size_t)d * HW;
        pS0 = (din && ok0) ? Sv[base + gb0] : 0.f;
        pM0 = (din && ok0) ? Mv[base + gb0] : 0.f;
        pS1 = (din && ok1) ? Sv[base + gb1] : 0.f;
        pM1 = (din && ok1) ? Mv[base + gb1] : 0.f;
        pS2 = (din && ok2) ? Sv[base + gb2] : 0.f;
        pM2 = (din && ok2) ? Mv[base + gb2] : 0.f;
    };
    auto commit = [&](int d) {
        float* __restrict__ bS = &buf[d & 1][0][0];
        float* __restrict__ bM = &buf[d & 1][1][0];
        bS[tid] = pS0;        bM[tid] = pM0;
        bS[tid + 256] = pS1;  bM[tid + 256] = pM1;
        if (has2) { bS[tid + 512] = pS2; bM[tid + 512] = pM2; }
    };

    // stencil window: halo rows r..r+2, halo cols tw2..tw2+3 (4 consecutive
    // floats per row = two 8B-aligned v2f loads -> ds_read2_b64)
    const int rb = r * LSTR + tw2;
    auto fieldPartials = [&](const float* __restrict__ b,
                             v2f& Px, v2f& Py, v2f& Bq, v2f& Cq) {
        const float* p0 = b + rb;
        const float* p1 = p0 + LSTR;
        const float* p2 = p1 + LSTR;
        v2f lo0 = *(const v2f*)p0, hi0 = *(const v2f*)(p0 + 2);
        v2f lo1 = *(const v2f*)p1, hi1 = *(const v2f*)(p1 + 2);
        v2f lo2 = *(const v2f*)p2, hi2 = *(const v2f*)(p2 + 2);
        v2f X0 = hi0 - lo0, X1 = hi1 - lo1, X2 = hi2 - lo2;
        v2f m0 = (v2f){lo0.y, hi0.x};
        v2f m1 = (v2f){lo1.y, hi1.x};
        v2f m2 = (v2f){lo2.y, hi2.x};
        v2f s0 = lo0 + hi0, s1 = lo1 + hi1, s2 = lo2 + hi2;
        v2f W0 = __builtin_elementwise_fma(m0, (v2f)(2.f), s0);
        v2f W2 = __builtin_elementwise_fma(m2, (v2f)(2.f), s2);
        v2f I0 = s0 + m0, I1 = s1 + m1, I2 = s2 + m2;
        Px = __builtin_elementwise_fma(X1, (v2f)(2.f), X0) + X2;  // vert [1,2,1] of X
        Py = W2 - W0;                                             // vert [-1,0,1] of W
        Bq = __builtin_elementwise_fma(I1, (v2f)(2.f), I0) + I2;  // vert [1,2,1] of I
        Cq = m1;                                                  // center values
    };

    // register ring: named v2f per slice {m,z,p} x field {S,M} x {Px,Py,B,C}
    v2f mSPx, mSPy, mSB, mSC, mMPx, mMPy, mMB, mMC;
    v2f zSPx, zSPy, zSB, zSC, zMPx, zMPy, zMB, zMC;
    v2f pSPx, pSPy, pSB, pSC, pMPx, pMPy, pMB, pMC;

    // ---- warmup (new ordering: issue always AFTER the barrier) ----
    issue(d0 - 1);
    commit(d0 - 1);          // fully exposed wait (first touch, unavoidable)
    __syncthreads();
    issue(d0);               // in flight across partials(m)
    fieldPartials(&buf[(d0 - 1) & 1][0][0], mSPx, mSPy, mSB, mSC);
    fieldPartials(&buf[(d0 - 1) & 1][1][0], mMPx, mMPy, mMB, mMC);
    commit(d0);
    __syncthreads();
    issue(d0 + 1);           // in flight across partials(z)
    const size_t voff = (size_t)(h0 + r) * WW + (w0 + tw2);   // pair contiguous
    v2f fFx, fFy, fFz;
    {
        size_t o = (size_t)d0 * HW + voff;
        fFx = *(const v2f*)(flow + o);
        fFy = *(const v2f*)(flow + NVOX + o);
        fFz = *(const v2f*)(flow + 2 * (size_t)NVOX + o);
    }
    fieldPartials(&buf[d0 & 1][0][0], zSPx, zSPy, zSB, zSC);
    fieldPartials(&buf[d0 & 1][1][0], zMPx, zMPy, zMB, zMC);

    v2f vsum = (v2f){0.f, 0.f};

    #pragma unroll
    for (int dd = 0; dd < TD; ++dd) {
        const int d = d0 + dd;
        commit(d + 1);       // waits on loads in flight since after LAST barrier
        __syncthreads();     // zero outstanding VMEM here -> drain is free
        v2f nFx = (v2f){0.f, 0.f}, nFy = nFx, nFz = nFx;
        if (dd < TD - 1) {
            issue(d + 2);    // flies across partials + compute below
            size_t o = (size_t)(d + 1) * HW + voff;
            nFx = *(const v2f*)(flow + o);
            nFy = *(const v2f*)(flow + NVOX + o);
            nFz = *(const v2f*)(flow + 2 * (size_t)NVOX + o);
        }
        fieldPartials(&buf[(d + 1) & 1][0][0], pSPx, pSPy, pSB, pSC);
        fieldPartials(&buf[(d + 1) & 1][1][0], pMPx, pMPy, pMB, pMC);

        v2f idf = zMC - zSC;
        v2f i2  = __builtin_elementwise_fma(idf, idf, (v2f)(1e-10f));
        v2f gxS = mSPx + zSPx + pSPx;
        v2f gyS = mSPy + zSPy + pSPy;
        v2f gzS = pSB - mSB;
        v2f gxM = mMPx + zMPx + pMPx;
        v2f gyM = mMPy + zMPy + pMPy;
        v2f gzM = pMB - mMB;
        v2f denS = __builtin_elementwise_fma(gxS, gxS,
                   __builtin_elementwise_fma(gyS, gyS,
                   __builtin_elementwise_fma(gzS, gzS, i2)));
        v2f denM = __builtin_elementwise_fma(gxM, gxM,
                   __builtin_elementwise_fma(gyM, gyM,
                   __builtin_elementwise_fma(gzM, gzM, i2)));
        v2f rS = vrcp(denS);
        v2f rM = vrcp(denM);
        v2f Ux = idf * __builtin_elementwise_fma(gxS, rS, gxM * rM);
        v2f Uy = idf * __builtin_elementwise_fma(gyS, rS, gyM * rM);
        v2f Uz = idf * __builtin_elementwise_fma(gzS, rS, gzM * rM);

        v2f uzp = Uz + 1e-10f;
        v2f dxz = atan_ratio(Ux, uzp);
        v2f dyz = atan_ratio(Uy, uzp);

        v2f fzp = fFz + 1e-10f;
        v2f fxz = atan_ratio(fFx, fzp);
        v2f fyz = atan_ratio(fFy, fzp);

        v2f e1 = fxz - dxz;
        v2f e2 = fyz - dyz;
        vsum = __builtin_elementwise_fma(e1, e1,
               __builtin_elementwise_fma(e2, e2, vsum));

        // rotate ring (renamed by full unroll)
        mSPx = zSPx; mSPy = zSPy; mSB = zSB; mSC = zSC;
        mMPx = zMPx; mMPy = zMPy; mMB = zMB; mMC = zMC;
        zSPx = pSPx; zSPy = pSPy; zSB = pSB; zSC = pSC;
        zMPx = pMPx; zMPy = pMPy; zMB = pMB; zMC = pMC;
        fFx = nFx; fFy = nFy; fFz = nFz;
    }

    float lsum = vsum.x + vsum.y;
    // wave shuffle reduce -> per-wave LDS slot -> one atomic per block
    #pragma unroll
    for (int o = 32; o > 0; o >>= 1)
        lsum += __shfl_down(lsum, o, 64);
    if (lane == 0)
        redbuf[wid] = lsum;
    __syncthreads();
    if (tid == 0) {
        float s = redbuf[0] + redbuf[1] + redbuf[2] + redbuf[3];
        atomicAdd(out, s * (1.0f / (float)NVOX));
    }
}

extern "C" void kernel_launch(void* const* d_in, const int* in_sizes, int n_in,
                              void* d_out, int out_size, void* d_ws, size_t ws_size,
                              hipStream_t stream) {
    const float* Mv   = (const float*)d_in[0];
    const float* Sv   = (const float*)d_in[1];
    const float* flow = (const float*)d_in[2];
    float* out = (float*)d_out;

    hipMemsetAsync(out, 0, sizeof(float), stream);

    dim3 grid(WW / TW, HH / THB, DD / TD);   // 5 x 12 x 20 = 1200 blocks
    demons_ori_kernel<<<grid, dim3(256), 0, stream>>>(Mv, Sv, flow, out);
}

// Round 8
// 129.548 us; speedup vs baseline: 1.5696x; 1.1901x over previous
//
#include <hip/hip_runtime.h>
#include <math.h>

#define DD 160
#define HH 192
#define WW 160
#define TW 32          // block tile width
#define THB 16         // block tile height (16 rows x 16 w-pairs = 256 threads)
#define TD 8           // slices per block -> 1200 blocks
#define HW (HH * WW)
#define NVOX (DD * HW)
#define HTW 34         // halo cols
#define HTH 18         // halo rows
#define LSTR 34        // row stride == HTW keeps staging LINEAR
#define PHALO 612      // one plane's halo floats
#define PAIRH 1224     // two planes staged per barrier round

typedef float v2f __attribute__((ext_vector_type(2)));

__device__ __forceinline__ v2f vrcp(v2f a) {
    v2f r;
    r.x = __builtin_amdgcn_rcpf(a.x);
    r.y = __builtin_amdgcn_rcpf(a.y);
    return r;
}

// packed atan(num/den) with a SINGLE rcp (absmax 0.0 through R2-R6).
__device__ __forceinline__ v2f atan_ratio(v2f num, v2f den) {
    v2f a = __builtin_elementwise_abs(num);
    v2f b = __builtin_elementwise_abs(den);
    v2f mn = __builtin_elementwise_min(a, b);
    v2f mx = __builtin_elementwise_max(a, b);
    v2f x = mn * vrcp(mx);
    v2f x2 = x * x;
    v2f p = __builtin_elementwise_fma(x2,
            __builtin_elementwise_fma(x2,
            __builtin_elementwise_fma(x2,
            __builtin_elementwise_fma(x2,
            __builtin_elementwise_fma(x2, (v2f)(-0.0117212f), (v2f)(0.05265332f)),
            (v2f)(-0.11643287f)), (v2f)(0.19354346f)), (v2f)(-0.33262347f)),
            (v2f)(0.99997726f));
    p *= x;
    v2f q = 1.57079632679489662f - p;
    v2f res;
    res.x = a.x > b.x ? q.x : p.x;   // res >= 0 here
    res.y = a.y > b.y ? q.y : p.y;
    unsigned sx = (__float_as_uint(num.x) ^ __float_as_uint(den.x)) & 0x80000000u;
    unsigned sy = (__float_as_uint(num.y) ^ __float_as_uint(den.y)) & 0x80000000u;
    res.x = __uint_as_float(__float_as_uint(res.x) | sx);
    res.y = __uint_as_float(__float_as_uint(res.y) | sy);
    return res;
}

struct Part { v2f Px, Py, B, C; };

// R15: z-unroll-2 on the exact R2 (41us) structure. R1/R2 established
// time ~ barrier-round count (stages x1.2 -> time x1.21; -25% instrs at
// same stages -> no change). Two slices per barrier round: block stages
// 10 -> 6 (total 12000 -> 7200). Pair of planes staged as ONE linear
// 1224-float region per field, double-buffered (same WAR discipline as
// R2). Ring = 4 planes (m,z,p,q); everything else byte-identical R2.
__global__ __launch_bounds__(256) void demons_ori_kernel(
    const float* __restrict__ Mv, const float* __restrict__ Sv,
    const float* __restrict__ flow, float* __restrict__ out)
{
    __shared__ float buf[2][2][PAIRH];   // [parity][field][pair slot]
    __shared__ float redbuf[4];

    const int tid = threadIdx.x;
    const int lane = tid & 63;
    const int wid = tid >> 6;
    const int i16 = lane & 15;                  // w-pair index 0..15
    const int r   = wid * 4 + (lane >> 4);      // voxel row 0..15
    const int tw2 = 2 * i16;                    // block-local first col of pair
    const int w0 = blockIdx.x * TW;
    const int h0 = blockIdx.y * THB;
    const int d0 = blockIdx.z * TD;

    // slice-invariant staging slots: i = tid + 256*s, s=0..4 (s=4: tid<200).
    // pl = which plane of the pair, gb = in-plane global offset.
    const bool has4 = (tid < PAIRH - 1024);   // tids 0..199
    int gb0, gb1, gb2, gb3, gb4 = 0;
    int pl0, pl1, pl2, pl3, pl4 = 0;
    bool ok0, ok1, ok2, ok3, ok4 = false;
    {
        int i, j, hh, ww, gh, gw;
        i = tid;           pl0 = 0;            j = i;
        hh = j / HTW; ww = j - HTW * hh; gh = h0 + hh - 1; gw = w0 + ww - 1;
        ok0 = (gh >= 0 && gh < HH && gw >= 0 && gw < WW); gb0 = gh * WW + gw;
        i = tid + 256;     pl1 = (i >= PHALO); j = i - PHALO * pl1;
        hh = j / HTW; ww = j - HTW * hh; gh = h0 + hh - 1; gw = w0 + ww - 1;
        ok1 = (gh >= 0 && gh < HH && gw >= 0 && gw < WW); gb1 = gh * WW + gw;
        i = tid + 512;     pl2 = (i >= PHALO); j = i - PHALO * pl2;
        hh = j / HTW; ww = j - HTW * hh; gh = h0 + hh - 1; gw = w0 + ww - 1;
        ok2 = (gh >= 0 && gh < HH && gw >= 0 && gw < WW); gb2 = gh * WW + gw;
        i = tid + 768;     pl3 = 1;            j = i - PHALO;
        hh = j / HTW; ww = j - HTW * hh; gh = h0 + hh - 1; gw = w0 + ww - 1;
        ok3 = (gh >= 0 && gh < HH && gw >= 0 && gw < WW); gb3 = gh * WW + gw;
        if (has4) {
            i = tid + 1024; pl4 = 1;           j = i - PHALO;
            hh = j / HTW; ww = j - HTW * hh; gh = h0 + hh - 1; gw = w0 + ww - 1;
            ok4 = (gh >= 0 && gh < HH && gw >= 0 && gw < WW); gb4 = gh * WW + gw;
        }
    }

    // distance-1 prefetch set — named scalars only (R3/R6 lesson)
    float hS0 = 0.f, hM0 = 0.f, hS1 = 0.f, hM1 = 0.f, hS2 = 0.f, hM2 = 0.f;
    float hS3 = 0.f, hM3 = 0.f, hS4 = 0.f, hM4 = 0.f;

    // issue pair (planes e, e+1)
    auto issue = [&](int e) {
        int dp; bool o; size_t a;
        dp = e + pl0; o = ok0 && ((unsigned)dp < (unsigned)DD);
        a = (size_t)dp * HW + gb0;
        hS0 = o ? Sv[a] : 0.f;  hM0 = o ? Mv[a] : 0.f;
        dp = e + pl1; o = ok1 && ((unsigned)dp < (unsigned)DD);
        a = (size_t)dp * HW + gb1;
        hS1 = o ? Sv[a] : 0.f;  hM1 = o ? Mv[a] : 0.f;
        dp = e + pl2; o = ok2 && ((unsigned)dp < (unsigned)DD);
        a = (size_t)dp * HW + gb2;
        hS2 = o ? Sv[a] : 0.f;  hM2 = o ? Mv[a] : 0.f;
        dp = e + pl3; o = ok3 && ((unsigned)dp < (unsigned)DD);
        a = (size_t)dp * HW + gb3;
        hS3 = o ? Sv[a] : 0.f;  hM3 = o ? Mv[a] : 0.f;
        dp = e + pl4; o = ok4 && ((unsigned)dp < (unsigned)DD);
        a = (size_t)dp * HW + gb4;
        hS4 = o ? Sv[a] : 0.f;  hM4 = o ? Mv[a] : 0.f;
    };
    auto commit = [&](int par) {
        float* __restrict__ bS = &buf[par][0][0];
        float* __restrict__ bM = &buf[par][1][0];
        bS[tid] = hS0;         bM[tid] = hM0;
        bS[tid + 256] = hS1;   bM[tid + 256] = hM1;
        bS[tid + 512] = hS2;   bM[tid + 512] = hM2;
        bS[tid + 768] = hS3;   bM[tid + 768] = hM3;
        if (has4) { bS[tid + 1024] = hS4; bM[tid + 1024] = hM4; }
    };

    // stencil window within one staged plane (identical to R2)
    const int rb = r * LSTR + tw2;
    auto fieldPartials = [&](const float* __restrict__ b, Part& P) {
        const float* p0 = b + rb;
        const float* p1 = p0 + LSTR;
        const float* p2 = p1 + LSTR;
        v2f lo0 = *(const v2f*)p0, hi0 = *(const v2f*)(p0 + 2);
        v2f lo1 = *(const v2f*)p1, hi1 = *(const v2f*)(p1 + 2);
        v2f lo2 = *(const v2f*)p2, hi2 = *(const v2f*)(p2 + 2);
        v2f X0 = hi0 - lo0, X1 = hi1 - lo1, X2 = hi2 - lo2;
        v2f m0 = (v2f){lo0.y, hi0.x};
        v2f m1 = (v2f){lo1.y, hi1.x};
        v2f m2 = (v2f){lo2.y, hi2.x};
        v2f s0 = lo0 + hi0, s1 = lo1 + hi1, s2 = lo2 + hi2;
        v2f W0 = __builtin_elementwise_fma(m0, (v2f)(2.f), s0);
        v2f W2 = __builtin_elementwise_fma(m2, (v2f)(2.f), s2);
        v2f I0 = s0 + m0, I1 = s1 + m1, I2 = s2 + m2;
        P.Px = __builtin_elementwise_fma(X1, (v2f)(2.f), X0) + X2;
        P.Py = W2 - W0;
        P.B  = __builtin_elementwise_fma(I1, (v2f)(2.f), I0) + I2;
        P.C  = m1;
    };

    v2f vsum = (v2f){0.f, 0.f};

    // one slice's demons term (identical math to R2)
    auto sliceTerm = [&](const Part& mS, const Part& zS, const Part& pS,
                         const Part& mM, const Part& zM, const Part& pM,
                         v2f fx, v2f fy, v2f fz) {
        v2f idf = zM.C - zS.C;
        v2f i2  = __builtin_elementwise_fma(idf, idf, (v2f)(1e-10f));
        v2f gxS = mS.Px + zS.Px + pS.Px;
        v2f gyS = mS.Py + zS.Py + pS.Py;
        v2f gzS = pS.B - mS.B;
        v2f gxM = mM.Px + zM.Px + pM.Px;
        v2f gyM = mM.Py + zM.Py + pM.Py;
        v2f gzM = pM.B - mM.B;
        v2f denS = __builtin_elementwise_fma(gxS, gxS,
                   __builtin_elementwise_fma(gyS, gyS,
                   __builtin_elementwise_fma(gzS, gzS, i2)));
        v2f denM = __builtin_elementwise_fma(gxM, gxM,
                   __builtin_elementwise_fma(gyM, gyM,
                   __builtin_elementwise_fma(gzM, gzM, i2)));
        v2f rS = vrcp(denS);
        v2f rM = vrcp(denM);
        v2f Ux = idf * __builtin_elementwise_fma(gxS, rS, gxM * rM);
        v2f Uy = idf * __builtin_elementwise_fma(gyS, rS, gyM * rM);
        v2f Uz = idf * __builtin_elementwise_fma(gzS, rS, gzM * rM);
        v2f uzp = Uz + 1e-10f;
        v2f dxz = atan_ratio(Ux, uzp);
        v2f dyz = atan_ratio(Uy, uzp);
        v2f fzp = fz + 1e-10f;
        v2f fxz = atan_ratio(fx, fzp);
        v2f fyz = atan_ratio(fy, fzp);
        v2f e1 = fxz - dxz;
        v2f e2 = fyz - dyz;
        vsum = __builtin_elementwise_fma(e1, e1,
               __builtin_elementwise_fma(e2, e2, vsum));
    };

    // register ring over z: planes {m,z,p,q} x fields {S,M}
    Part mS, zS, pS, qS, mM, zM, pM, qM;

    // ---- warmup (R2 ordering: commit; issue-next; barrier) ----
    issue(d0 - 1);                 // pair A = planes (d0-1, d0)
    commit(1);                     // parity 1; exposed wait (first touch)
    issue(d0 + 1);                 // pair B = planes (d0+1, d0+2), in flight
    __syncthreads();
    fieldPartials(&buf[1][0][0], mS);              // P(d0-1)
    fieldPartials(&buf[1][1][0], mM);
    fieldPartials(&buf[1][0][PHALO], zS);          // P(d0)
    fieldPartials(&buf[1][1][PHALO], zM);

    const size_t voff = (size_t)(h0 + r) * WW + (w0 + tw2);
    v2f fAx, fAy, fAz, fBx, fBy, fBz;   // flow for slices d, d+1
    {
        size_t o = (size_t)d0 * HW + voff;
        fAx = *(const v2f*)(flow + o);
        fAy = *(const v2f*)(flow + NVOX + o);
        fAz = *(const v2f*)(flow + 2 * (size_t)NVOX + o);
        o += HW;
        fBx = *(const v2f*)(flow + o);
        fBy = *(const v2f*)(flow + NVOX + o);
        fBz = *(const v2f*)(flow + 2 * (size_t)NVOX + o);
    }

    #pragma unroll
    for (int k = 0; k < TD / 2; ++k) {
        const int d = d0 + 2 * k;
        const int par = k & 1;
        commit(par);                 // pair (d+1, d+2): loads in flight one round
        v2f nAx = (v2f){0.f, 0.f}, nAy = nAx, nAz = nAx;
        v2f nBx = nAx, nBy = nAx, nBz = nAx;
        if (k < TD / 2 - 1) {
            issue(d + 3);            // pair (d+3, d+4), flies across this round
            size_t o = (size_t)(d + 2) * HW + voff;
            nAx = *(const v2f*)(flow + o);
            nAy = *(const v2f*)(flow + NVOX + o);
            nAz = *(const v2f*)(flow + 2 * (size_t)NVOX + o);
            o += HW;
            nBx = *(const v2f*)(flow + o);
            nBy = *(const v2f*)(flow + NVOX + o);
            nBz = *(const v2f*)(flow + 2 * (size_t)NVOX + o);
        }
        __syncthreads();
        fieldPartials(&buf[par][0][0], pS);            // P(d+1)
        fieldPartials(&buf[par][1][0], pM);
        sliceTerm(mS, zS, pS, mM, zM, pM, fAx, fAy, fAz);      // slice d
        fieldPartials(&buf[par][0][PHALO], qS);        // P(d+2)
        fieldPartials(&buf[par][1][PHALO], qM);
        sliceTerm(zS, pS, qS, zM, pM, qM, fBx, fBy, fBz);      // slice d+1

        // rotate ring by 2 (renamed by full unroll)
        mS = pS; zS = qS;
        mM = pM; zM = qM;
        fAx = nAx; fAy = nAy; fAz = nAz;
        fBx = nBx; fBy = nBy; fBz = nBz;
    }

    float lsum = vsum.x + vsum.y;
    // wave shuffle reduce -> per-wave LDS slot -> one atomic per block
    #pragma unroll
    for (int o = 32; o > 0; o >>= 1)
        lsum += __shfl_down(lsum, o, 64);
    if (lane == 0)
        redbuf[wid] = lsum;
    __syncthreads();
    if (tid == 0) {
        float s = redbuf[0] + redbuf[1] + redbuf[2] + redbuf[3];
        atomicAdd(out, s * (1.0f / (float)NVOX));
    }
}

extern "C" void kernel_launch(void* const* d_in, const int* in_sizes, int n_in,
                              void* d_out, int out_size, void* d_ws, size_t ws_size,
                              hipStream_t stream) {
    const float* Mv   = (const float*)d_in[0];
    const float* Sv   = (const float*)d_in[1];
    const float* flow = (const float*)d_in[2];
    float* out = (float*)d_out;

    hipMemsetAsync(out, 0, sizeof(float), stream);

    dim3 grid(WW / TW, HH / THB, DD / TD);   // 5 x 12 x 20 = 1200 blocks
    demons_ori_kernel<<<grid, dim3(256), 0, stream>>>(Mv, Sv, flow, out);
}